// Round 1
// baseline (1696.155 us; speedup 1.0000x reference)
//
#include <hip/hip_runtime.h>

#define NN 50000     // nodes
#define NE 800000    // edges per metapath
#define NP 4         // metapaths
#define DIN 256      // in_size
#define DD 256       // out dim (out_size * heads)
#define NH 128       // semantic attention hidden

// ---------------- CSR build ----------------

__global__ void deg_kernel(const int* __restrict__ src, const int* __restrict__ dst,
                           int* __restrict__ deg_out, int* __restrict__ deg_in) {
  int i = blockIdx.x * blockDim.x + threadIdx.x;
  if (i >= NP * NE) return;
  int p = i / NE;
  atomicAdd(&deg_out[p * NN + src[i]], 1);
  atomicAdd(&deg_in[p * NN + dst[i]], 1);
}

__global__ void scan_kernel(const int* __restrict__ deg_in, int* __restrict__ row_ptr,
                            int* __restrict__ cursor) {
  int p = blockIdx.x;
  const int* d = deg_in + (size_t)p * NN;
  int* rp = row_ptr + (size_t)p * (NN + 1);
  int* cu = cursor + (size_t)p * NN;
  __shared__ int sm[1024];
  __shared__ int carry;
  if (threadIdx.x == 0) carry = 0;
  __syncthreads();
  for (int base = 0; base < NN; base += 1024) {
    int i = base + (int)threadIdx.x;
    int v = (i < NN) ? d[i] : 0;
    sm[threadIdx.x] = v;
    __syncthreads();
    for (int off = 1; off < 1024; off <<= 1) {
      int t = (threadIdx.x >= (unsigned)off) ? sm[threadIdx.x - off] : 0;
      __syncthreads();
      sm[threadIdx.x] += t;
      __syncthreads();
    }
    int excl = carry + sm[threadIdx.x] - v;
    if (i < NN) { rp[i] = excl; cu[i] = excl; }
    __syncthreads();
    if (threadIdx.x == 1023) carry += sm[1023];
    __syncthreads();
  }
  if (threadIdx.x == 0) rp[NN] = carry;
}

__global__ void fill_kernel(const int* __restrict__ src, const int* __restrict__ dst,
                            int* __restrict__ cursor, int* __restrict__ col) {
  int i = blockIdx.x * blockDim.x + threadIdx.x;
  if (i >= NP * NE) return;
  int p = i / NE;
  int pos = atomicAdd(&cursor[p * NN + dst[i]], 1);
  col[(size_t)p * NE + pos] = src[i];
}

// ---------------- aggregation: g_p = D_in^{-1/2} A_p D_out^{-1/2} h ----------------
// one wave (64 lanes) per dst node; each lane holds 4 of the 256 features.

__global__ __launch_bounds__(256) void agg_kernel(
    const float* __restrict__ h, const int* __restrict__ col,
    const int* __restrict__ row_ptr, const int* __restrict__ deg_out,
    const int* __restrict__ deg_in, float* __restrict__ g) {
  int p = blockIdx.y;
  int v = blockIdx.x * 4 + (threadIdx.x >> 6);
  int lane = threadIdx.x & 63;
  const int* colp = col + (size_t)p * NE;
  const int* rpp = row_ptr + (size_t)p * (NN + 1);
  const int* dop = deg_out + (size_t)p * NN;
  int beg = rpp[v], end = rpp[v + 1];
  float ax = 0.f, ay = 0.f, az = 0.f, aw = 0.f;
  for (int j = beg; j < end; ++j) {
    int s = colp[j];
    float r = rsqrtf(fmaxf((float)dop[s], 1.0f));
    float4 hv = ((const float4*)(h + (size_t)s * DIN))[lane];
    ax = fmaf(r, hv.x, ax);
    ay = fmaf(r, hv.y, ay);
    az = fmaf(r, hv.z, az);
    aw = fmaf(r, hv.w, aw);
  }
  float ri = rsqrtf(fmaxf((float)deg_in[(size_t)p * NN + v], 1.0f));
  ((float4*)(g + ((size_t)p * NN + v) * DIN))[lane] =
      make_float4(ax * ri, ay * ri, az * ri, aw * ri);
}

// ---------------- tiny precomputes: M_p = W_p @ W1, c_p = b_p @ W1 + b1 ----------------

__global__ void wmul_kernel(const float* __restrict__ Wgc, const float* __restrict__ W1,
                            float* __restrict__ Mmat) {
  int p = blockIdx.y, k = blockIdx.x, j = threadIdx.x;  // block = 128
  const float* wrow = Wgc + ((size_t)p * DIN + k) * DD;
  float s = 0.f;
  for (int d = 0; d < DD; ++d) s = fmaf(wrow[d], W1[(size_t)d * NH + j], s);
  Mmat[((size_t)p * DIN + k) * NH + j] = s;
}

__global__ void cvec_kernel(const float* __restrict__ bgc, const float* __restrict__ W1,
                            const float* __restrict__ b1, float* __restrict__ cvec) {
  int p = blockIdx.x, j = threadIdx.x;  // block = 128
  const float* b = bgc + (size_t)p * DD;
  float s = b1[j];
  for (int d = 0; d < DD; ++d) s = fmaf(b[d], W1[(size_t)d * NH + j], s);
  cvec[p * NH + j] = s;
}

// ---------------- semantic attention partial sums ----------------
// ssum[p] = sum_n tanh(g_p[n] @ M_p + c_p) . w2     (128x128 tile GEMM + fused epilogue)

__global__ __launch_bounds__(256) void gemm_sem(
    const float* __restrict__ g, const float* __restrict__ Mmat,
    const float* __restrict__ cvec, const float* __restrict__ w2,
    float* __restrict__ ssum) {
  __shared__ float As[8][132];
  __shared__ float Bs[8][132];
  __shared__ float sred[16 * 132];
  __shared__ float sblk[128];
  const int tid = threadIdx.x;
  const int tx = tid & 15, ty = tid >> 4;
  const int p = blockIdx.y;
  const int row0 = blockIdx.x * 128;
  const int la_row = tid >> 1;
  const int la_half = (tid & 1) * 4;
  const int lb_k = tid >> 5;
  const int lb_col = (tid & 31) * 4;
  int ar = row0 + la_row;
  if (ar >= NN) ar = NN - 1;  // clamped loads; masked at reduction
  const float* Ap = g + ((size_t)p * NN + ar) * DIN;
  const float* Bp = Mmat + (size_t)p * DIN * NH;
  float acc[2][2][4][4] = {};
  for (int k2 = 0; k2 < DIN; k2 += 8) {
    float4 av = *(const float4*)(Ap + k2 + la_half);
    float4 bv = *(const float4*)(Bp + (size_t)(k2 + lb_k) * NH + lb_col);
    __syncthreads();
    As[la_half + 0][la_row] = av.x;
    As[la_half + 1][la_row] = av.y;
    As[la_half + 2][la_row] = av.z;
    As[la_half + 3][la_row] = av.w;
    *(float4*)&Bs[lb_k][lb_col] = bv;
    __syncthreads();
#pragma unroll
    for (int k = 0; k < 8; ++k) {
      float4 a0 = *(const float4*)&As[k][ty * 4];
      float4 a1 = *(const float4*)&As[k][64 + ty * 4];
      float4 b0 = *(const float4*)&Bs[k][tx * 4];
      float4 b1 = *(const float4*)&Bs[k][64 + tx * 4];
      float a[2][4] = {{a0.x, a0.y, a0.z, a0.w}, {a1.x, a1.y, a1.z, a1.w}};
      float b[2][4] = {{b0.x, b0.y, b0.z, b0.w}, {b1.x, b1.y, b1.z, b1.w}};
#pragma unroll
      for (int rg = 0; rg < 2; ++rg)
#pragma unroll
        for (int cg = 0; cg < 2; ++cg)
#pragma unroll
          for (int i = 0; i < 4; ++i)
#pragma unroll
            for (int j = 0; j < 4; ++j)
              acc[rg][cg][i][j] = fmaf(a[rg][i], b[cg][j], acc[rg][cg][i][j]);
    }
  }
  // epilogue: tanh(acc + c) . w2, reduce over cols then rows
  const float* cp = cvec + p * NH;
  float4 cv0 = *(const float4*)(cp + tx * 4);
  float4 cv1 = *(const float4*)(cp + 64 + tx * 4);
  float4 wv0 = *(const float4*)(w2 + tx * 4);
  float4 wv1 = *(const float4*)(w2 + 64 + tx * 4);
  float c[2][4] = {{cv0.x, cv0.y, cv0.z, cv0.w}, {cv1.x, cv1.y, cv1.z, cv1.w}};
  float w[2][4] = {{wv0.x, wv0.y, wv0.z, wv0.w}, {wv1.x, wv1.y, wv1.z, wv1.w}};
#pragma unroll
  for (int rg = 0; rg < 2; ++rg)
#pragma unroll
    for (int i = 0; i < 4; ++i) {
      float pr = 0.f;
#pragma unroll
      for (int cg = 0; cg < 2; ++cg)
#pragma unroll
        for (int j = 0; j < 4; ++j)
          pr = fmaf(tanhf(acc[rg][cg][i][j] + c[cg][j]), w[cg][j], pr);
      sred[tx * 132 + rg * 64 + ty * 4 + i] = pr;
    }
  __syncthreads();
  if (tid < 128) {
    float s = 0.f;
#pragma unroll
    for (int x = 0; x < 16; ++x) s += sred[x * 132 + tid];
    sblk[tid] = (row0 + tid < NN) ? s : 0.f;
  }
  __syncthreads();
  if (tid < 64) {
    float v = sblk[tid] + sblk[tid + 64];
#pragma unroll
    for (int o = 32; o > 0; o >>= 1) v += __shfl_down(v, o);
    if (tid == 0) atomicAdd(&ssum[p], v);
  }
}

// ---------------- beta = softmax(ssum / N); bout = sum_p beta_p b_p ----------------

__global__ void beta_kernel(const float* __restrict__ ssum, const float* __restrict__ bgc,
                            float* __restrict__ beta, float* __restrict__ bout) {
  __shared__ float sb[NP];
  if (threadIdx.x == 0) {
    float m[NP];
    float mx = -1e30f;
    for (int p = 0; p < NP; ++p) {
      m[p] = ssum[p] / (float)NN;
      mx = fmaxf(mx, m[p]);
    }
    float tot = 0.f;
    for (int p = 0; p < NP; ++p) {
      m[p] = expf(m[p] - mx);
      tot += m[p];
    }
    for (int p = 0; p < NP; ++p) {
      sb[p] = m[p] / tot;
      beta[p] = sb[p];
    }
  }
  __syncthreads();
  int d = threadIdx.x;  // block = 256
  float s = 0.f;
  for (int p = 0; p < NP; ++p) s = fmaf(sb[p], bgc[p * DD + d], s);
  bout[d] = s;
}

// ---------------- main GEMM: out = [g_0|g_1|g_2|g_3] @ [beta_p W_p] + bout ----------------

__global__ __launch_bounds__(256) void gemm_main(
    const float* __restrict__ g, const float* __restrict__ Wgc,
    const float* __restrict__ beta, const float* __restrict__ bout,
    float* __restrict__ out) {
  __shared__ float As[8][132];
  __shared__ float Bs[8][132];
  const int tid = threadIdx.x;
  const int tx = tid & 15, ty = tid >> 4;
  const int row0 = blockIdx.x * 128;
  const int col0 = blockIdx.y * 128;
  const int la_row = tid >> 1;
  const int la_half = (tid & 1) * 4;
  const int lb_k = tid >> 5;
  const int lb_col = (tid & 31) * 4;
  int ar = row0 + la_row;
  if (ar >= NN) ar = NN - 1;  // clamped loads; stores guarded
  float acc[2][2][4][4] = {};
  for (int p = 0; p < NP; ++p) {
    const float sb = beta[p];
    const float* Ap = g + ((size_t)p * NN + ar) * DIN;
    const float* Bp = Wgc + (size_t)p * DIN * DD;
    for (int k2 = 0; k2 < DIN; k2 += 8) {
      float4 av = *(const float4*)(Ap + k2 + la_half);
      float4 bv = *(const float4*)(Bp + (size_t)(k2 + lb_k) * DD + col0 + lb_col);
      __syncthreads();
      As[la_half + 0][la_row] = av.x;
      As[la_half + 1][la_row] = av.y;
      As[la_half + 2][la_row] = av.z;
      As[la_half + 3][la_row] = av.w;
      *(float4*)&Bs[lb_k][lb_col] =
          make_float4(bv.x * sb, bv.y * sb, bv.z * sb, bv.w * sb);
      __syncthreads();
#pragma unroll
      for (int k = 0; k < 8; ++k) {
        float4 a0 = *(const float4*)&As[k][ty * 4];
        float4 a1 = *(const float4*)&As[k][64 + ty * 4];
        float4 b0 = *(const float4*)&Bs[k][tx * 4];
        float4 b1 = *(const float4*)&Bs[k][64 + tx * 4];
        float a[2][4] = {{a0.x, a0.y, a0.z, a0.w}, {a1.x, a1.y, a1.z, a1.w}};
        float b[2][4] = {{b0.x, b0.y, b0.z, b0.w}, {b1.x, b1.y, b1.z, b1.w}};
#pragma unroll
        for (int rg = 0; rg < 2; ++rg)
#pragma unroll
          for (int cg = 0; cg < 2; ++cg)
#pragma unroll
            for (int i = 0; i < 4; ++i)
#pragma unroll
              for (int j = 0; j < 4; ++j)
                acc[rg][cg][i][j] = fmaf(a[rg][i], b[cg][j], acc[rg][cg][i][j]);
      }
    }
  }
  float4 bo0 = *(const float4*)(bout + col0 + tx * 4);
  float4 bo1 = *(const float4*)(bout + col0 + 64 + tx * 4);
  float bb[2][4] = {{bo0.x, bo0.y, bo0.z, bo0.w}, {bo1.x, bo1.y, bo1.z, bo1.w}};
#pragma unroll
  for (int rg = 0; rg < 2; ++rg)
#pragma unroll
    for (int i = 0; i < 4; ++i) {
      int r = row0 + rg * 64 + ty * 4 + i;
      if (r < NN) {
#pragma unroll
        for (int cg = 0; cg < 2; ++cg) {
          float4 o = make_float4(acc[rg][cg][i][0] + bb[cg][0],
                                 acc[rg][cg][i][1] + bb[cg][1],
                                 acc[rg][cg][i][2] + bb[cg][2],
                                 acc[rg][cg][i][3] + bb[cg][3]);
          *(float4*)(out + (size_t)r * DD + col0 + cg * 64 + tx * 4) = o;
        }
      }
    }
}

// ---------------- launcher ----------------

extern "C" void kernel_launch(void* const* d_in, const int* in_sizes, int n_in,
                              void* d_out, int out_size, void* d_ws, size_t ws_size,
                              hipStream_t stream) {
  const float* h = (const float*)d_in[0];
  const int* src = (const int*)d_in[1];
  const int* dst = (const int*)d_in[2];
  const float* Wgc = (const float*)d_in[3];
  const float* bgc = (const float*)d_in[4];
  const float* W1 = (const float*)d_in[5];
  const float* b1 = (const float*)d_in[6];
  const float* w2 = (const float*)d_in[7];
  float* out = (float*)d_out;

  char* base = (char*)d_ws;
  size_t off = 0;
  auto alloc = [&](size_t bytes) -> char* {
    char* ptr = base + off;
    off = (off + bytes + 255) & ~(size_t)255;
    return ptr;
  };
  int* degs = (int*)alloc((size_t)2 * NP * NN * sizeof(int));  // deg_out | deg_in
  int* deg_out_i = degs;
  int* deg_in_i = degs + (size_t)NP * NN;
  int* row_ptr = (int*)alloc((size_t)NP * (NN + 1) * sizeof(int));
  int* cursor = (int*)alloc((size_t)NP * NN * sizeof(int));
  int* colbuf = (int*)alloc((size_t)NP * NE * sizeof(int));
  float* g = (float*)alloc((size_t)NP * NN * DIN * sizeof(float));
  float* Mmat = (float*)alloc((size_t)NP * DIN * NH * sizeof(float));
  float* cvec = (float*)alloc((size_t)NP * NH * sizeof(float));
  float* ssum = (float*)alloc(NP * sizeof(float));
  float* beta = (float*)alloc(NP * sizeof(float));
  float* bout = (float*)alloc(DD * sizeof(float));
  if (off > ws_size) return;  // insufficient workspace -> fail loudly

  hipMemsetAsync(degs, 0, (size_t)2 * NP * NN * sizeof(int), stream);
  hipMemsetAsync(ssum, 0, NP * sizeof(float), stream);

  deg_kernel<<<(NP * NE + 255) / 256, 256, 0, stream>>>(src, dst, deg_out_i, deg_in_i);
  scan_kernel<<<NP, 1024, 0, stream>>>(deg_in_i, row_ptr, cursor);
  fill_kernel<<<(NP * NE + 255) / 256, 256, 0, stream>>>(src, dst, cursor, colbuf);
  agg_kernel<<<dim3(NN / 4, NP), 256, 0, stream>>>(h, colbuf, row_ptr, deg_out_i,
                                                   deg_in_i, g);
  wmul_kernel<<<dim3(DIN, NP), NH, 0, stream>>>(Wgc, W1, Mmat);
  cvec_kernel<<<NP, NH, 0, stream>>>(bgc, W1, b1, cvec);
  gemm_sem<<<dim3((NN + 127) / 128, NP), 256, 0, stream>>>(g, Mmat, cvec, w2, ssum);
  beta_kernel<<<1, 256, 0, stream>>>(ssum, bgc, beta, bout);
  gemm_main<<<dim3((NN + 127) / 128, 2), 256, 0, stream>>>(g, Wgc, beta, bout, out);
}

// Round 2
// 1095.392 us; speedup vs baseline: 1.5484x; 1.5484x over previous
//
#include <hip/hip_runtime.h>

#define NN 50000     // nodes
#define NE 800000    // edges per metapath
#define NP 4         // metapaths
#define DIN 256      // in_size
#define DD 256       // out dim
#define NH 128       // semantic attention hidden
#define SA 40        // LDS row stride in bf16 elems (80 B: optimal bank packing for b128)

typedef __attribute__((ext_vector_type(8))) short bf16x8;
typedef __attribute__((ext_vector_type(4))) float f32x4;

__device__ __forceinline__ unsigned short f2bf(float f) {
  unsigned u = __float_as_uint(f);
  u += 0x7fff + ((u >> 16) & 1);  // RNE
  return (unsigned short)(u >> 16);
}
__device__ __forceinline__ float bfl(unsigned u) { return __uint_as_float(u << 16); }
__device__ __forceinline__ float bfh(unsigned u) { return __uint_as_float(u & 0xffff0000u); }

// ---------------- CSR build ----------------

__global__ void deg_kernel(const int* __restrict__ src, const int* __restrict__ dst,
                           int* __restrict__ deg_out, int* __restrict__ deg_in) {
  int i = blockIdx.x * blockDim.x + threadIdx.x;
  if (i >= NP * NE) return;
  int p = i / NE;
  atomicAdd(&deg_out[p * NN + src[i]], 1);
  atomicAdd(&deg_in[p * NN + dst[i]], 1);
}

__global__ void rsq_kernel(const int* __restrict__ deg, float* __restrict__ rsq) {
  int i = blockIdx.x * blockDim.x + threadIdx.x;
  if (i >= 2 * NP * NN) return;
  rsq[i] = rsqrtf(fmaxf((float)deg[i], 1.f));
}

__global__ void scan_kernel(const int* __restrict__ deg_in, int* __restrict__ row_ptr,
                            int* __restrict__ cursor) {
  int p = blockIdx.x;
  const int* d = deg_in + (size_t)p * NN;
  int* rp = row_ptr + (size_t)p * (NN + 1);
  int* cu = cursor + (size_t)p * NN;
  __shared__ int sm[1024];
  __shared__ int carry;
  if (threadIdx.x == 0) carry = 0;
  __syncthreads();
  for (int base = 0; base < NN; base += 1024) {
    int i = base + (int)threadIdx.x;
    int v = (i < NN) ? d[i] : 0;
    sm[threadIdx.x] = v;
    __syncthreads();
    for (int off = 1; off < 1024; off <<= 1) {
      int t = (threadIdx.x >= (unsigned)off) ? sm[threadIdx.x - off] : 0;
      __syncthreads();
      sm[threadIdx.x] += t;
      __syncthreads();
    }
    int excl = carry + sm[threadIdx.x] - v;
    if (i < NN) { rp[i] = excl; cu[i] = excl; }
    __syncthreads();
    if (threadIdx.x == 1023) carry += sm[1023];
    __syncthreads();
  }
  if (threadIdx.x == 0) rp[NN] = carry;
}

__global__ void fill_kernel(const int* __restrict__ src, const int* __restrict__ dst,
                            int* __restrict__ cursor, int* __restrict__ col) {
  int i = blockIdx.x * blockDim.x + threadIdx.x;
  if (i >= NP * NE) return;
  int p = i / NE;
  int pos = atomicAdd(&cursor[p * NN + dst[i]], 1);
  col[(size_t)p * NE + pos] = src[i];
}

// ---------------- h -> bf16 ----------------

__global__ void cvt_h_kernel(const float4* __restrict__ h4, ushort4* __restrict__ h2) {
  int i = blockIdx.x * blockDim.x + threadIdx.x;
  if (i >= NN * DIN / 4) return;
  float4 v = h4[i];
  ushort4 o;
  o.x = f2bf(v.x); o.y = f2bf(v.y); o.z = f2bf(v.z); o.w = f2bf(v.w);
  h2[i] = o;
}

// ---------------- aggregation: g_p = rin * sum_src rout[src] * h2[src] (bf16 out) ----------

__global__ __launch_bounds__(256) void agg_kernel(
    const ushort* __restrict__ h2, const int* __restrict__ col,
    const int* __restrict__ row_ptr, const float* __restrict__ rout,
    const float* __restrict__ rin, ushort* __restrict__ g) {
  int p = blockIdx.y;
  int v = blockIdx.x * 4 + (threadIdx.x >> 6);
  int lane = threadIdx.x & 63;
  const int* colp = col + (size_t)p * NE;
  const float* rop = rout + (size_t)p * NN;
  int beg = row_ptr[p * (NN + 1) + v], end = row_ptr[p * (NN + 1) + v + 1];
  const uint2* hv = (const uint2*)h2;
  float a0 = 0, a1 = 0, a2 = 0, a3 = 0, b0 = 0, b1 = 0, b2 = 0, b3 = 0;
  int j = beg;
  for (; j + 1 < end; j += 2) {
    int s0 = colp[j], s1 = colp[j + 1];
    float r0 = rop[s0], r1 = rop[s1];
    uint2 u0 = hv[(size_t)s0 * 64 + lane];
    uint2 u1 = hv[(size_t)s1 * 64 + lane];
    a0 = fmaf(r0, bfl(u0.x), a0); a1 = fmaf(r0, bfh(u0.x), a1);
    a2 = fmaf(r0, bfl(u0.y), a2); a3 = fmaf(r0, bfh(u0.y), a3);
    b0 = fmaf(r1, bfl(u1.x), b0); b1 = fmaf(r1, bfh(u1.x), b1);
    b2 = fmaf(r1, bfl(u1.y), b2); b3 = fmaf(r1, bfh(u1.y), b3);
  }
  if (j < end) {
    int s0 = colp[j];
    float r0 = rop[s0];
    uint2 u0 = hv[(size_t)s0 * 64 + lane];
    a0 = fmaf(r0, bfl(u0.x), a0); a1 = fmaf(r0, bfh(u0.x), a1);
    a2 = fmaf(r0, bfl(u0.y), a2); a3 = fmaf(r0, bfh(u0.y), a3);
  }
  float ri = rin[(size_t)p * NN + v];
  ushort4 o;
  o.x = f2bf((a0 + b0) * ri); o.y = f2bf((a1 + b1) * ri);
  o.z = f2bf((a2 + b2) * ri); o.w = f2bf((a3 + b3) * ri);
  ((ushort4*)(g + ((size_t)p * NN + v) * DIN))[lane] = o;
}

// ---------------- Mt_p = (W_p @ W1)^T  (bf16, n-major), c_p = b_p @ W1 + b1 ----------------

__global__ void wmul_kernel(const float* __restrict__ Wgc, const float* __restrict__ W1,
                            ushort* __restrict__ Mt) {
  int p = blockIdx.y, k = blockIdx.x, j = threadIdx.x;  // block = 128
  const float* wrow = Wgc + ((size_t)p * DIN + k) * DD;
  float s = 0.f;
  for (int d = 0; d < DD; ++d) s = fmaf(wrow[d], W1[(size_t)d * NH + j], s);
  Mt[((size_t)p * NH + j) * DIN + k] = f2bf(s);
}

__global__ void cvec_kernel(const float* __restrict__ bgc, const float* __restrict__ W1,
                            const float* __restrict__ b1, float* __restrict__ cvec) {
  int p = blockIdx.x, j = threadIdx.x;  // block = 128
  const float* b = bgc + (size_t)p * DD;
  float s = b1[j];
  for (int d = 0; d < DD; ++d) s = fmaf(b[d], W1[(size_t)d * NH + j], s);
  cvec[p * NH + j] = s;
}

// ---------------- gemm_sem: ssum[p] = sum_{n,c} tanh(g_p @ M_p + c)[n,c] * w2[c] --------

__global__ __launch_bounds__(256) void gemm_sem(
    const ushort* __restrict__ g, const ushort* __restrict__ Mt,
    const float* __restrict__ cvec, const float* __restrict__ w2,
    float* __restrict__ ssum) {
  __shared__ ushort As[128 * SA];
  __shared__ ushort Bs[128 * SA];
  __shared__ float wsum[4];
  const int tid = threadIdx.x;
  const int p = blockIdx.y;
  const int row0 = blockIdx.x * 128;
  const int wave = tid >> 6, lane = tid & 63;
  const int wr = wave >> 1, wc = wave & 1;
  const int srow = tid >> 2, sseg = tid & 3;
  const int fr = lane & 15, fk = (lane >> 4) * 8;
  const ushort* Ag = g + (size_t)p * NN * DIN;
  const ushort* Bg = Mt + (size_t)p * NH * DIN;
  int ar0 = row0 + srow; if (ar0 >= NN) ar0 = NN - 1;
  int ar1 = row0 + srow + 64; if (ar1 >= NN) ar1 = NN - 1;
  f32x4 acc[4][4] = {};
  for (int k2 = 0; k2 < DIN; k2 += 32) {
    uint4 av0 = *(const uint4*)(Ag + (size_t)ar0 * DIN + k2 + sseg * 8);
    uint4 av1 = *(const uint4*)(Ag + (size_t)ar1 * DIN + k2 + sseg * 8);
    uint4 bv0 = *(const uint4*)(Bg + (size_t)srow * DIN + k2 + sseg * 8);
    uint4 bv1 = *(const uint4*)(Bg + (size_t)(srow + 64) * DIN + k2 + sseg * 8);
    __syncthreads();
    *(uint4*)&As[srow * SA + sseg * 8] = av0;
    *(uint4*)&As[(srow + 64) * SA + sseg * 8] = av1;
    *(uint4*)&Bs[srow * SA + sseg * 8] = bv0;
    *(uint4*)&Bs[(srow + 64) * SA + sseg * 8] = bv1;
    __syncthreads();
    bf16x8 af[4], bfv[4];
#pragma unroll
    for (int t = 0; t < 4; ++t) {
      af[t] = *(const bf16x8*)&As[(wr * 64 + t * 16 + fr) * SA + fk];
      bfv[t] = *(const bf16x8*)&Bs[(wc * 64 + t * 16 + fr) * SA + fk];
    }
#pragma unroll
    for (int mt = 0; mt < 4; ++mt)
#pragma unroll
      for (int nt = 0; nt < 4; ++nt)
        acc[mt][nt] = __builtin_amdgcn_mfma_f32_16x16x32_bf16(af[mt], bfv[nt], acc[mt][nt], 0, 0, 0);
  }
  float s = 0.f;
#pragma unroll
  for (int nt = 0; nt < 4; ++nt) {
    int c = wc * 64 + nt * 16 + fr;
    float cc = cvec[p * NH + c];
    float ww = w2[c];
#pragma unroll
    for (int mt = 0; mt < 4; ++mt)
#pragma unroll
      for (int i = 0; i < 4; ++i) {
        int r = row0 + wr * 64 + mt * 16 + (lane >> 4) * 4 + i;
        if (r < NN) {
          float x = acc[mt][nt][i] + cc;
          x = fminf(fmaxf(x, -15.f), 15.f);
          float e = __expf(2.f * x);
          s = fmaf((e - 1.f) / (e + 1.f), ww, s);
        }
      }
  }
#pragma unroll
  for (int o = 32; o > 0; o >>= 1) s += __shfl_down(s, o);
  if (lane == 0) wsum[wave] = s;
  __syncthreads();
  if (tid == 0) atomicAdd(&ssum[p], wsum[0] + wsum[1] + wsum[2] + wsum[3]);
}

// ---------------- beta + bout + beta-scaled W^T (bf16) ----------------

__global__ void beta_kernel(const float* __restrict__ ssum, const float* __restrict__ bgc,
                            float* __restrict__ beta, float* __restrict__ bout) {
  __shared__ float sb[NP];
  if (threadIdx.x == 0) {
    float m[NP];
    float mx = -1e30f;
    for (int p = 0; p < NP; ++p) {
      m[p] = ssum[p] / (float)NN;
      mx = fmaxf(mx, m[p]);
    }
    float tot = 0.f;
    for (int p = 0; p < NP; ++p) { m[p] = expf(m[p] - mx); tot += m[p]; }
    for (int p = 0; p < NP; ++p) { sb[p] = m[p] / tot; beta[p] = sb[p]; }
  }
  __syncthreads();
  int d = threadIdx.x;  // block = 256
  float s = 0.f;
  for (int p = 0; p < NP; ++p) s = fmaf(sb[p], bgc[p * DD + d], s);
  bout[d] = s;
}

__global__ void scaleWt_kernel(const float* __restrict__ Wgc, const float* __restrict__ beta,
                               ushort* __restrict__ Wt) {
  int i = blockIdx.x * blockDim.x + threadIdx.x;  // over DD * NP * DIN
  if (i >= DD * NP * DIN) return;
  int n = i >> 10;
  int pk = i & 1023;
  int p = pk >> 8, k = pk & 255;
  Wt[i] = f2bf(beta[p] * Wgc[((size_t)p * DIN + k) * DD + n]);
}

// ---------------- gemm_main: out = [g_0|..|g_3] @ Wt^T + bout ----------------

__global__ __launch_bounds__(256) void gemm_main(
    const ushort* __restrict__ g, const ushort* __restrict__ Wt,
    const float* __restrict__ bout, float* __restrict__ out) {
  __shared__ ushort As[128 * SA];
  __shared__ ushort Bs[128 * SA];
  const int tid = threadIdx.x;
  const int row0 = blockIdx.x * 128;
  const int col0 = blockIdx.y * 128;
  const int wave = tid >> 6, lane = tid & 63;
  const int wr = wave >> 1, wc = wave & 1;
  const int srow = tid >> 2, sseg = tid & 3;
  const int fr = lane & 15, fk = (lane >> 4) * 8;
  int ar0 = row0 + srow; if (ar0 >= NN) ar0 = NN - 1;
  int ar1 = row0 + srow + 64; if (ar1 >= NN) ar1 = NN - 1;
  f32x4 acc[4][4] = {};
  for (int p = 0; p < NP; ++p) {
    const ushort* Ag = g + (size_t)p * NN * DIN;
    for (int k2 = 0; k2 < DIN; k2 += 32) {
      uint4 av0 = *(const uint4*)(Ag + (size_t)ar0 * DIN + k2 + sseg * 8);
      uint4 av1 = *(const uint4*)(Ag + (size_t)ar1 * DIN + k2 + sseg * 8);
      uint4 bv0 = *(const uint4*)(Wt + (size_t)(col0 + srow) * (NP * DIN) + p * DIN + k2 + sseg * 8);
      uint4 bv1 = *(const uint4*)(Wt + (size_t)(col0 + srow + 64) * (NP * DIN) + p * DIN + k2 + sseg * 8);
      __syncthreads();
      *(uint4*)&As[srow * SA + sseg * 8] = av0;
      *(uint4*)&As[(srow + 64) * SA + sseg * 8] = av1;
      *(uint4*)&Bs[srow * SA + sseg * 8] = bv0;
      *(uint4*)&Bs[(srow + 64) * SA + sseg * 8] = bv1;
      __syncthreads();
      bf16x8 af[4], bfv[4];
#pragma unroll
      for (int t = 0; t < 4; ++t) {
        af[t] = *(const bf16x8*)&As[(wr * 64 + t * 16 + fr) * SA + fk];
        bfv[t] = *(const bf16x8*)&Bs[(wc * 64 + t * 16 + fr) * SA + fk];
      }
#pragma unroll
      for (int mt = 0; mt < 4; ++mt)
#pragma unroll
        for (int nt = 0; nt < 4; ++nt)
          acc[mt][nt] = __builtin_amdgcn_mfma_f32_16x16x32_bf16(af[mt], bfv[nt], acc[mt][nt], 0, 0, 0);
    }
  }
#pragma unroll
  for (int nt = 0; nt < 4; ++nt) {
    int c = col0 + wc * 64 + nt * 16 + fr;
    float bb = bout[c];
#pragma unroll
    for (int mt = 0; mt < 4; ++mt)
#pragma unroll
      for (int i = 0; i < 4; ++i) {
        int r = row0 + wr * 64 + mt * 16 + (lane >> 4) * 4 + i;
        if (r < NN) out[(size_t)r * DD + c] = acc[mt][nt][i] + bb;
      }
  }
}

// ---------------- launcher ----------------

extern "C" void kernel_launch(void* const* d_in, const int* in_sizes, int n_in,
                              void* d_out, int out_size, void* d_ws, size_t ws_size,
                              hipStream_t stream) {
  const float* h = (const float*)d_in[0];
  const int* src = (const int*)d_in[1];
  const int* dst = (const int*)d_in[2];
  const float* Wgc = (const float*)d_in[3];
  const float* bgc = (const float*)d_in[4];
  const float* W1 = (const float*)d_in[5];
  const float* b1 = (const float*)d_in[6];
  const float* w2 = (const float*)d_in[7];
  float* out = (float*)d_out;

  char* base = (char*)d_ws;
  size_t off = 0;
  auto alloc = [&](size_t bytes) -> char* {
    char* ptr = base + off;
    off = (off + bytes + 255) & ~(size_t)255;
    return ptr;
  };
  int* degs = (int*)alloc((size_t)2 * NP * NN * sizeof(int));
  int* deg_out_i = degs;
  int* deg_in_i = degs + (size_t)NP * NN;
  float* rsq = (float*)alloc((size_t)2 * NP * NN * sizeof(float));
  float* rout = rsq;
  float* rin = rsq + (size_t)NP * NN;
  int* row_ptr = (int*)alloc((size_t)NP * (NN + 1) * sizeof(int));
  int* cursor = (int*)alloc((size_t)NP * NN * sizeof(int));
  int* colbuf = (int*)alloc((size_t)NP * NE * sizeof(int));
  ushort* h2 = (ushort*)alloc((size_t)NN * DIN * sizeof(ushort));
  ushort* g = (ushort*)alloc((size_t)NP * NN * DIN * sizeof(ushort));
  ushort* Mt = (ushort*)alloc((size_t)NP * NH * DIN * sizeof(ushort));
  ushort* Wt = (ushort*)alloc((size_t)DD * NP * DIN * sizeof(ushort));
  float* cvec = (float*)alloc((size_t)NP * NH * sizeof(float));
  float* ssum = (float*)alloc(NP * sizeof(float));
  float* beta = (float*)alloc(NP * sizeof(float));
  float* bout = (float*)alloc(DD * sizeof(float));
  if (off > ws_size) return;

  hipMemsetAsync(degs, 0, (size_t)2 * NP * NN * sizeof(int), stream);
  hipMemsetAsync(ssum, 0, NP * sizeof(float), stream);

  deg_kernel<<<(NP * NE + 255) / 256, 256, 0, stream>>>(src, dst, deg_out_i, deg_in_i);
  rsq_kernel<<<(2 * NP * NN + 255) / 256, 256, 0, stream>>>(degs, rsq);
  scan_kernel<<<NP, 1024, 0, stream>>>(deg_in_i, row_ptr, cursor);
  fill_kernel<<<(NP * NE + 255) / 256, 256, 0, stream>>>(src, dst, cursor, colbuf);
  cvt_h_kernel<<<(NN * DIN / 4 + 255) / 256, 256, 0, stream>>>((const float4*)h, (ushort4*)h2);
  agg_kernel<<<dim3(NN / 4, NP), 256, 0, stream>>>(h2, colbuf, row_ptr, rout, rin, g);
  wmul_kernel<<<dim3(DIN, NP), NH, 0, stream>>>(Wgc, W1, Mt);
  cvec_kernel<<<NP, NH, 0, stream>>>(bgc, W1, b1, cvec);
  gemm_sem<<<dim3((NN + 127) / 128, NP), 256, 0, stream>>>(g, Mt, cvec, w2, ssum);
  beta_kernel<<<1, 256, 0, stream>>>(ssum, bgc, beta, bout);
  scaleWt_kernel<<<(DD * NP * DIN + 255) / 256, 256, 0, stream>>>(Wgc, beta, Wt);
  gemm_main<<<dim3((NN + 127) / 128, 2), 256, 0, stream>>>(g, Wt, bout, out);
}